// Round 5
// baseline (163.123 us; speedup 1.0000x reference)
//
#include <hip/hip_runtime.h>
#include <cmath>

#define BB 16
#define CC 512
#define HWH 4096
#define NH 8
#define DK 64
#define PL 128

typedef float fx4 __attribute__((ext_vector_type(4)));

__device__ __forceinline__ float wred_sum(float v){
#pragma unroll
  for (int m = 32; m >= 1; m >>= 1) v += __shfl_xor(v, m, 64);
  return v;
}

// ---------------- K1: partial logits, c-split x4, float4 over p ----------------
// epart[cc][b][n][p] = sum_{c in chunk cc} x[b,c,p] * cmw[n,c]
// grid 256 = b(16) x ptile(4) x cc(4), block 256 (thread owns 4 positions)
__global__ __launch_bounds__(256) void k_logits(const float* __restrict__ x,
                                                const float* __restrict__ cmw,
                                                float* __restrict__ epart) {
  int bid = blockIdx.x;
  int cc = bid & 3;
  int tile = (bid >> 2) & 3;
  int b = bid >> 4;
  int p = tile * 1024 + threadIdx.x * 4;
  const float* xb = x + ((size_t)(b * CC + cc * 128)) * HWH + p;
  const float* wb = cmw + cc * 128;
  float acc[NH][4];
#pragma unroll
  for (int n = 0; n < NH; n++)
#pragma unroll
    for (int k = 0; k < 4; k++) acc[n][k] = 0.f;
#pragma unroll 4
  for (int c = 0; c < 128; c++) {
    float4 xv = *reinterpret_cast<const float4*>(xb + (size_t)c * HWH);
#pragma unroll
    for (int n = 0; n < NH; n++) {
      float w = wb[n * CC + c];
      acc[n][0] = fmaf(xv.x, w, acc[n][0]);
      acc[n][1] = fmaf(xv.y, w, acc[n][1]);
      acc[n][2] = fmaf(xv.z, w, acc[n][2]);
      acc[n][3] = fmaf(xv.w, w, acc[n][3]);
    }
  }
  float* ob = epart + (((size_t)(cc * BB + b)) * NH) * HWH + p;
#pragma unroll
  for (int n = 0; n < NH; n++) {
    float4 o = make_float4(acc[n][0], acc[n][1], acc[n][2], acc[n][3]);
    *reinterpret_cast<float4*>(ob + (size_t)n * HWH) = o;
  }
}

// ---------------- K2: sum 4 partials + per-(b,n) softmax over 4096 ----------------
// stores UNNORMALIZED exp into e; meta[0..127]=inv_sum,[128..255]=cx,[256..383]=cy
// grid 128, block 256 (thread owns 4 chunks of float4)
__global__ __launch_bounds__(256) void k_softmax(const float* __restrict__ epart,
                                                 float* __restrict__ e,
                                                 float* __restrict__ meta) {
  __shared__ float sr[4][4];
  int bn = blockIdx.x;
  int t = threadIdx.x;
  float* row = e + (size_t)bn * HWH;
  float4 v[4];
  float lmax = -1e30f;
#pragma unroll
  for (int i = 0; i < 4; i++) {
    int idx = t * 4 + i * 1024;
    const float* r = epart + (size_t)bn * HWH + idx;
    float4 a = *reinterpret_cast<const float4*>(r);
#pragma unroll
    for (int cc = 1; cc < 4; cc++) {
      float4 pth = *reinterpret_cast<const float4*>(r + (size_t)cc * BB * NH * HWH);
      a.x += pth.x; a.y += pth.y; a.z += pth.z; a.w += pth.w;
    }
    v[i] = a;
    lmax = fmaxf(lmax, fmaxf(fmaxf(a.x, a.y), fmaxf(a.z, a.w)));
  }
#pragma unroll
  for (int m = 32; m >= 1; m >>= 1) lmax = fmaxf(lmax, __shfl_xor(lmax, m, 64));
  if ((t & 63) == 0) sr[0][t >> 6] = lmax;
  __syncthreads();
  lmax = fmaxf(fmaxf(sr[0][0], sr[0][1]), fmaxf(sr[0][2], sr[0][3]));
  float s = 0.f, sc = 0.f, sy = 0.f;
#pragma unroll
  for (int i = 0; i < 4; i++) {
    int idx = t * 4 + i * 1024;
    float4 ev;
    ev.x = expf(v[i].x - lmax);
    ev.y = expf(v[i].y - lmax);
    ev.z = expf(v[i].z - lmax);
    ev.w = expf(v[i].w - lmax);
    *reinterpret_cast<float4*>(row + idx) = ev;
    float col = (float)(idx & 63);
    float rw  = (float)(idx >> 6);
    s += ev.x + ev.y + ev.z + ev.w;
    sc += ev.x * col + ev.y * (col + 1.f) + ev.z * (col + 2.f) + ev.w * (col + 3.f);
    sy += (ev.x + ev.y + ev.z + ev.w) * rw;
  }
  s = wred_sum(s); sc = wred_sum(sc); sy = wred_sum(sy);
  if ((t & 63) == 0) { sr[1][t >> 6] = s; sr[2][t >> 6] = sc; sr[3][t >> 6] = sy; }
  __syncthreads();
  if (t == 0) {
    s  = sr[1][0] + sr[1][1] + sr[1][2] + sr[1][3];
    sc = sr[2][0] + sr[2][1] + sr[2][2] + sr[2][3];
    sy = sr[3][0] + sr[3][1] + sr[3][2] + sr[3][3];
    meta[bn]       = 1.f / s;
    meta[128 + bn] = sc / (s * 64.f);   // cx
    meta[256 + bn] = sy / (s * 64.f);   // cy
  }
}

// ---------------- K3: context, register-only ----------------
// pctx[ng][b][h][c] = sum_{n in half ng} x[b,c,n] * e[b,h,n]
// grid 512 = b(16) x cg(16) x ng(2), block 512 = 8 waves.
__global__ __launch_bounds__(512) void k_context(const float* __restrict__ x,
                                                 const float* __restrict__ e,
                                                 float* __restrict__ pctx) {
  int bid = blockIdx.x;
  int ng = bid & 1;
  int cg = (bid >> 1) & 15;
  int b = bid >> 5;
  int w = threadIdx.x >> 6;
  int l = threadIdx.x & 63;
  int cbase = cg * 32 + w * 4;
  const float* xb = x + ((size_t)(b * CC + cbase)) * HWH + ng * 2048 + l * 4;
  const float* eb = e + (size_t)b * NH * HWH + ng * 2048 + l * 4;
  float acc[4][NH];
#pragma unroll
  for (int ci = 0; ci < 4; ci++)
#pragma unroll
    for (int h = 0; h < NH; h++) acc[ci][h] = 0.f;

#pragma unroll 2
  for (int ch = 0; ch < 8; ch++) {   // 8 chunks of 256 n
    int off = ch * 256;
    float4 ev[NH];
#pragma unroll
    for (int h = 0; h < NH; h++)
      ev[h] = *reinterpret_cast<const float4*>(eb + (size_t)h * HWH + off);
#pragma unroll
    for (int ci = 0; ci < 4; ci++) {
      float4 xv = *reinterpret_cast<const float4*>(xb + (size_t)ci * HWH + off);
#pragma unroll
      for (int h = 0; h < NH; h++) {
        float a = acc[ci][h];
        a = fmaf(xv.x, ev[h].x, a);
        a = fmaf(xv.y, ev[h].y, a);
        a = fmaf(xv.z, ev[h].z, a);
        a = fmaf(xv.w, ev[h].w, a);
        acc[ci][h] = a;
      }
    }
  }
#pragma unroll
  for (int ci = 0; ci < 4; ci++)
#pragma unroll
    for (int h = 0; h < NH; h++) acc[ci][h] = wred_sum(acc[ci][h]);
  if (l == 0) {
    float* op = pctx + (((size_t)(ng * BB + b)) * NH) * CC + cbase;
#pragma unroll
    for (int h = 0; h < NH; h++)
#pragma unroll
      for (int ci = 0; ci < 4; ci++) op[h * CC + ci] = acc[ci][h];
  }
}

// ---------------- K4: kqv projections, 8-way split dots ----------------
// grid 384 = b(16) x j(3) x h(8), block 512
__global__ __launch_bounds__(512) void k_kqv(const float* __restrict__ pctx,
    const float* __restrict__ meta,
    const float* __restrict__ k_w, const float* __restrict__ q_w,
    const float* __restrict__ v_w,
    const float* __restrict__ k_b, const float* __restrict__ q_b,
    const float* __restrict__ v_b,
    float* __restrict__ kqvbuf) {
  int bid = blockIdx.x;
  int b = bid / 24;
  int r = bid - b * 24;
  int j = r >> 3;
  int h = r & 7;
  int t = threadIdx.x;
  __shared__ float ctx[8 * 68];
  __shared__ float psum[64][9];
  float inv = meta[b * NH + h];
  size_t base = ((size_t)b * NH + h) * CC + t;
  float cval = (pctx[base] + pctx[(size_t)BB * NH * CC + base]) * inv;
  ctx[(t >> 6) * 68 + (t & 63)] = cval;
  __syncthreads();
  const float* wm = (j == 0) ? k_w : (j == 1) ? q_w : v_w;
  const float* bm = (j == 0) ? k_b : (j == 1) ? q_b : v_b;
  int d = t >> 3, s = t & 7;
  const float* wr = wm + d * CC + s * 64;
  const float* cl = ctx + s * 68;
  float a = 0.f;
#pragma unroll
  for (int c = 0; c < 64; c += 4) {
    float4 w4 = *reinterpret_cast<const float4*>(wr + c);
    a = fmaf(w4.x, cl[c + 0], a);
    a = fmaf(w4.y, cl[c + 1], a);
    a = fmaf(w4.z, cl[c + 2], a);
    a = fmaf(w4.w, cl[c + 3], a);
  }
  psum[d][s] = a;
  __syncthreads();
  if (t < 64) {
    float rsum = 0.f;
#pragma unroll
    for (int ss = 0; ss < 8; ss++) rsum += psum[t][ss];
    kqvbuf[((size_t)(b * 3 + j) * NH + h) * DK + t] = rsum + bm[t];
  }
}

// ---------------- K5: geometry + head softmax + out_ctx + MLP ----------------
// grid 16, block 512
__global__ __launch_bounds__(512) void k_attn_mlp(const float* __restrict__ kqvbuf,
    const float* __restrict__ meta,
    const float* __restrict__ g_w, const float* __restrict__ g_b,
    const float* __restrict__ aw1, const float* __restrict__ ab1,
    const float* __restrict__ lng, const float* __restrict__ lnb,
    const float* __restrict__ aw2, const float* __restrict__ ab2,
    float* __restrict__ add_term) {
  int b = blockIdx.x;
  int t = threadIdx.x;
  __shared__ float kq[3][NH * 68];
  __shared__ float smn[NH][NH];
  __shared__ float cxl[NH], cyl[NH];
  __shared__ float oc[CC];
  __shared__ float part[4][PL];
  __shared__ float yl[PL];
  __shared__ float sr[2][2];

  if (t < NH) { cxl[t] = meta[128 + b * NH + t]; cyl[t] = meta[256 + b * NH + t]; }
  {
    int h = t >> 6, d = t & 63;
#pragma unroll
    for (int j = 0; j < 3; j++)
      kq[j][h * 68 + d] = kqvbuf[(size_t)(b * 3 + j) * 512 + t];
  }
  __syncthreads();

  if (t < 64) {
    int m = t >> 3, n = t & 7;
    float dx = cxl[m] - cxl[n];
    float dy = cyl[m] - cyl[n];
    float pos[4] = { fmaxf(dx, 0.f), fmaxf(-dx, 0.f), fmaxf(dy, 0.f), fmaxf(-dy, 0.f) };
    float a = g_b[0];
#pragma unroll
    for (int p = 0; p < 4; p++) {
#pragma unroll
      for (int f = 0; f < 8; f++) {
        float dm = expf(-0.8634694098727671f * (float)f);  // 1000^(-f/8)
        float ang = 100.f * pos[p] * dm;
        a = fmaf(sinf(ang), g_w[p * 8 + f], a);
        a = fmaf(cosf(ang), g_w[32 + p * 8 + f], a);
      }
    }
    float wgl = logf(fmaxf(fmaxf(a, 0.f), 1e-6f));
    float dot = 0.f;
#pragma unroll
    for (int dd = 0; dd < DK; dd++)
      dot = fmaf(kq[0][m * 68 + dd], kq[1][n * 68 + dd], dot);
    smn[m][n] = dot * 0.125f + wgl;
  }
  __syncthreads();
  if (t < 8) {
    float mx = -1e30f;
#pragma unroll
    for (int m = 0; m < NH; m++) mx = fmaxf(mx, smn[m][t]);
    float ssum = 0.f; float ex[NH];
#pragma unroll
    for (int m = 0; m < NH; m++) { ex[m] = expf(smn[m][t] - mx); ssum += ex[m]; }
#pragma unroll
    for (int m = 0; m < NH; m++) smn[m][t] = ex[m] / ssum;
  }
  __syncthreads();
  {
    int n = t >> 6, d = t & 63;
    float a = 0.f;
#pragma unroll
    for (int m = 0; m < NH; m++) a = fmaf(smn[m][n], kq[2][m * 68 + d], a);
    oc[t] = a;
  }
  __syncthreads();
  {
    int d = t & 127, p = t >> 7;
    const float* wr = aw1 + d * CC + p * 128;
    const float* ol = oc + p * 128;
    float a = 0.f;
#pragma unroll 8
    for (int c = 0; c < 128; c += 4) {
      float4 w4 = *reinterpret_cast<const float4*>(wr + c);
      a = fmaf(w4.x, ol[c + 0], a);
      a = fmaf(w4.y, ol[c + 1], a);
      a = fmaf(w4.z, ol[c + 2], a);
      a = fmaf(w4.w, ol[c + 3], a);
    }
    part[p][d] = a;
  }
  __syncthreads();
  float y = 0.f;
  if (t < PL) y = part[0][t] + part[1][t] + part[2][t] + part[3][t] + ab1[t];
  {
    float s  = (t < PL) ? y : 0.f;
    float sq = s * y;
    s = wred_sum(s); sq = wred_sum(sq);
    if (t < PL && (t & 63) == 0) { sr[0][t >> 6] = s; sr[1][t >> 6] = sq; }
  }
  __syncthreads();
  {
    float mu = (sr[0][0] + sr[0][1]) * (1.f / 128.f);
    float var = (sr[1][0] + sr[1][1]) * (1.f / 128.f) - mu * mu;
    float rstd = rsqrtf(var + 1e-5f);
    if (t < PL) yl[t] = fmaxf((y - mu) * rstd * lng[t] + lnb[t], 0.f);
  }
  __syncthreads();
  {
    const float* wr = aw2 + t * PL;
    float a = ab2[t];
#pragma unroll 8
    for (int pp = 0; pp < PL; pp += 4) {
      float4 w4 = *reinterpret_cast<const float4*>(wr + pp);
      a = fmaf(w4.x, yl[pp + 0], a);
      a = fmaf(w4.y, yl[pp + 1], a);
      a = fmaf(w4.z, yl[pp + 2], a);
      a = fmaf(w4.w, yl[pp + 3], a);
    }
    add_term[b * CC + t] = a;
  }
}

// ---------------- K6: out = x + add_term[b][c], nontemporal stores ----------------
__global__ __launch_bounds__(256) void k_add(const float* __restrict__ x,
                                             const float* __restrict__ add_term,
                                             float* __restrict__ out) {
  const fx4* x4 = reinterpret_cast<const fx4*>(x);
  fx4* o4 = reinterpret_cast<fx4*>(out);
  const size_t n4 = (size_t)BB * CC * HWH / 4;  // 8388608
  for (size_t i = (size_t)blockIdx.x * 256 + threadIdx.x; i < n4;
       i += (size_t)gridDim.x * 256) {
    fx4 v = x4[i];
    float a = add_term[i >> 10];
    v += a;
    __builtin_nontemporal_store(v, &o4[i]);
  }
}

extern "C" void kernel_launch(void* const* d_in, const int* in_sizes, int n_in,
                              void* d_out, int out_size, void* d_ws, size_t ws_size,
                              hipStream_t stream) {
  const float* x   = (const float*)d_in[0];
  const float* cmw = (const float*)d_in[1];
  // d_in[2] conv_mask_b: per-head constant -> softmax-invariant, unused
  const float* g_w = (const float*)d_in[3];
  const float* g_b = (const float*)d_in[4];
  const float* k_w = (const float*)d_in[5];
  const float* k_b = (const float*)d_in[6];
  const float* q_w = (const float*)d_in[7];
  const float* q_b = (const float*)d_in[8];
  const float* v_w = (const float*)d_in[9];
  const float* v_b = (const float*)d_in[10];
  const float* aw1 = (const float*)d_in[11];
  const float* ab1 = (const float*)d_in[12];
  const float* lng = (const float*)d_in[13];
  const float* lnb = (const float*)d_in[14];
  const float* aw2 = (const float*)d_in[15];
  const float* ab2 = (const float*)d_in[16];
  float* out = (float*)d_out;
  float* ws = (float*)d_ws;

  // layout (floats). epart dead after k_softmax -> reused for pctx/kqvbuf/add_term.
  float* epart    = ws;                 // [4][16][8][4096] = 2,097,152 (8 MB)
  float* e        = ws + 2097152;       // [16][8][4096]    =   524,288
  float* meta     = ws + 2621440;       // 384 (pad 512)
  float* pctx     = ws;                 // [2][16][8][512]  =   131,072 (alias epart)
  float* kqvbuf   = ws + 131072;        // [16][3][8][64]   =    24,576 (alias epart)
  float* add_term = ws + 155648;        // [16][512]        =     8,192 (alias epart)

  hipLaunchKernelGGL(k_logits,   dim3(256),  dim3(256), 0, stream, x, cmw, epart);
  hipLaunchKernelGGL(k_softmax,  dim3(128),  dim3(256), 0, stream, epart, e, meta);
  hipLaunchKernelGGL(k_context,  dim3(512),  dim3(512), 0, stream, x, e, pctx);
  hipLaunchKernelGGL(k_kqv,      dim3(384),  dim3(512), 0, stream, pctx, meta,
                     k_w, q_w, v_w, k_b, q_b, v_b, kqvbuf);
  hipLaunchKernelGGL(k_attn_mlp, dim3(16),   dim3(512), 0, stream, kqvbuf, meta,
                     g_w, g_b, aw1, ab1, lng, lnb, aw2, ab2, add_term);
  hipLaunchKernelGGL(k_add,      dim3(2048), dim3(256), 0, stream, x, add_term, out);
}

// Round 6
// 151.385 us; speedup vs baseline: 1.0775x; 1.0775x over previous
//
#include <hip/hip_runtime.h>
#include <cmath>

#define BB 16
#define CC 512
#define HWH 4096
#define NH 8
#define DK 64
#define PL 128
#define CS 8   // c-split for logits

__device__ __forceinline__ float wred_sum(float v){
#pragma unroll
  for (int m = 32; m >= 1; m >>= 1) v += __shfl_xor(v, m, 64);
  return v;
}

// ---------------- K1: partial logits, c-split x8, float4 over p ----------------
// epart[cc][b][n][p] = sum_{c in chunk cc} x[b,c,p] * cmw[n,c]
// grid 512 = b(16) x ptile(4) x cc(8), block 256 (thread owns 4 positions)
__global__ __launch_bounds__(256) void k_logits(const float* __restrict__ x,
                                                const float* __restrict__ cmw,
                                                float* __restrict__ epart) {
  int bid = blockIdx.x;
  int cc = bid & 7;
  int tile = (bid >> 3) & 3;
  int b = bid >> 5;
  int p = tile * 1024 + threadIdx.x * 4;
  const float* xb = x + ((size_t)(b * CC + cc * 64)) * HWH + p;
  const float* wb = cmw + cc * 64;
  float acc[NH][4];
#pragma unroll
  for (int n = 0; n < NH; n++)
#pragma unroll
    for (int k = 0; k < 4; k++) acc[n][k] = 0.f;
#pragma unroll 8
  for (int c = 0; c < 64; c++) {
    float4 xv = *reinterpret_cast<const float4*>(xb + (size_t)c * HWH);
#pragma unroll
    for (int n = 0; n < NH; n++) {
      float w = wb[n * CC + c];
      acc[n][0] = fmaf(xv.x, w, acc[n][0]);
      acc[n][1] = fmaf(xv.y, w, acc[n][1]);
      acc[n][2] = fmaf(xv.z, w, acc[n][2]);
      acc[n][3] = fmaf(xv.w, w, acc[n][3]);
    }
  }
  float* ob = epart + (((size_t)(cc * BB + b)) * NH) * HWH + p;
#pragma unroll
  for (int n = 0; n < NH; n++) {
    float4 o = make_float4(acc[n][0], acc[n][1], acc[n][2], acc[n][3]);
    *reinterpret_cast<float4*>(ob + (size_t)n * HWH) = o;
  }
}

// ---------------- K2: sum 8 partials + per-(b,n) softmax over 4096 ----------------
// stores UNNORMALIZED exp into e; meta[0..127]=inv_sum,[128..255]=cx,[256..383]=cy
// grid 128, block 256 (thread owns 4 chunks of float4)
__global__ __launch_bounds__(256) void k_softmax(const float* __restrict__ epart,
                                                 float* __restrict__ e,
                                                 float* __restrict__ meta) {
  __shared__ float sr[4][4];
  int bn = blockIdx.x;
  int t = threadIdx.x;
  float* row = e + (size_t)bn * HWH;
  float4 v[4];
  float lmax = -1e30f;
#pragma unroll
  for (int i = 0; i < 4; i++) {
    int idx = t * 4 + i * 1024;
    const float* r = epart + (size_t)bn * HWH + idx;
    float4 a = *reinterpret_cast<const float4*>(r);
#pragma unroll
    for (int cc = 1; cc < CS; cc++) {
      float4 pth = *reinterpret_cast<const float4*>(r + (size_t)cc * BB * NH * HWH);
      a.x += pth.x; a.y += pth.y; a.z += pth.z; a.w += pth.w;
    }
    v[i] = a;
    lmax = fmaxf(lmax, fmaxf(fmaxf(a.x, a.y), fmaxf(a.z, a.w)));
  }
#pragma unroll
  for (int m = 32; m >= 1; m >>= 1) lmax = fmaxf(lmax, __shfl_xor(lmax, m, 64));
  if ((t & 63) == 0) sr[0][t >> 6] = lmax;
  __syncthreads();
  lmax = fmaxf(fmaxf(sr[0][0], sr[0][1]), fmaxf(sr[0][2], sr[0][3]));
  float s = 0.f, sc = 0.f, sy = 0.f;
#pragma unroll
  for (int i = 0; i < 4; i++) {
    int idx = t * 4 + i * 1024;
    float4 ev;
    ev.x = expf(v[i].x - lmax);
    ev.y = expf(v[i].y - lmax);
    ev.z = expf(v[i].z - lmax);
    ev.w = expf(v[i].w - lmax);
    *reinterpret_cast<float4*>(row + idx) = ev;
    float col = (float)(idx & 63);
    float rw  = (float)(idx >> 6);
    s += ev.x + ev.y + ev.z + ev.w;
    sc += ev.x * col + ev.y * (col + 1.f) + ev.z * (col + 2.f) + ev.w * (col + 3.f);
    sy += (ev.x + ev.y + ev.z + ev.w) * rw;
  }
  s = wred_sum(s); sc = wred_sum(sc); sy = wred_sum(sy);
  if ((t & 63) == 0) { sr[1][t >> 6] = s; sr[2][t >> 6] = sc; sr[3][t >> 6] = sy; }
  __syncthreads();
  if (t == 0) {
    s  = sr[1][0] + sr[1][1] + sr[1][2] + sr[1][3];
    sc = sr[2][0] + sr[2][1] + sr[2][2] + sr[2][3];
    sy = sr[3][0] + sr[3][1] + sr[3][2] + sr[3][3];
    meta[bn]       = 1.f / s;
    meta[128 + bn] = sc / (s * 64.f);   // cx
    meta[256 + bn] = sy / (s * 64.f);   // cy
  }
}

// ---------------- K3: context, register-only ----------------
// pctx[ng][b][h][c] = sum_{n in half ng} x[b,c,n] * e[b,h,n]
// grid 512 = b(16) x cg(16) x ng(2), block 512 = 8 waves.
__global__ __launch_bounds__(512) void k_context(const float* __restrict__ x,
                                                 const float* __restrict__ e,
                                                 float* __restrict__ pctx) {
  int bid = blockIdx.x;
  int ng = bid & 1;
  int cg = (bid >> 1) & 15;
  int b = bid >> 5;
  int w = threadIdx.x >> 6;
  int l = threadIdx.x & 63;
  int cbase = cg * 32 + w * 4;
  const float* xb = x + ((size_t)(b * CC + cbase)) * HWH + ng * 2048 + l * 4;
  const float* eb = e + (size_t)b * NH * HWH + ng * 2048 + l * 4;
  float acc[4][NH];
#pragma unroll
  for (int ci = 0; ci < 4; ci++)
#pragma unroll
    for (int h = 0; h < NH; h++) acc[ci][h] = 0.f;

#pragma unroll 2
  for (int ch = 0; ch < 8; ch++) {   // 8 chunks of 256 n
    int off = ch * 256;
    float4 ev[NH];
#pragma unroll
    for (int h = 0; h < NH; h++)
      ev[h] = *reinterpret_cast<const float4*>(eb + (size_t)h * HWH + off);
#pragma unroll
    for (int ci = 0; ci < 4; ci++) {
      float4 xv = *reinterpret_cast<const float4*>(xb + (size_t)ci * HWH + off);
#pragma unroll
      for (int h = 0; h < NH; h++) {
        float a = acc[ci][h];
        a = fmaf(xv.x, ev[h].x, a);
        a = fmaf(xv.y, ev[h].y, a);
        a = fmaf(xv.z, ev[h].z, a);
        a = fmaf(xv.w, ev[h].w, a);
        acc[ci][h] = a;
      }
    }
  }
#pragma unroll
  for (int ci = 0; ci < 4; ci++)
#pragma unroll
    for (int h = 0; h < NH; h++) acc[ci][h] = wred_sum(acc[ci][h]);
  if (l == 0) {
    float* op = pctx + (((size_t)(ng * BB + b)) * NH) * CC + cbase;
#pragma unroll
    for (int h = 0; h < NH; h++)
#pragma unroll
      for (int ci = 0; ci < 4; ci++) op[h * CC + ci] = acc[ci][h];
  }
}

// ---------------- K4: kqv projections, 8-way split dots ----------------
// grid 384 = b(16) x j(3) x h(8), block 512
__global__ __launch_bounds__(512) void k_kqv(const float* __restrict__ pctx,
    const float* __restrict__ meta,
    const float* __restrict__ k_w, const float* __restrict__ q_w,
    const float* __restrict__ v_w,
    const float* __restrict__ k_b, const float* __restrict__ q_b,
    const float* __restrict__ v_b,
    float* __restrict__ kqvbuf) {
  int bid = blockIdx.x;
  int b = bid / 24;
  int r = bid - b * 24;
  int j = r >> 3;
  int h = r & 7;
  int t = threadIdx.x;
  __shared__ float ctx[8 * 68];
  __shared__ float psum[64][9];
  float inv = meta[b * NH + h];
  size_t base = ((size_t)b * NH + h) * CC + t;
  float cval = (pctx[base] + pctx[(size_t)BB * NH * CC + base]) * inv;
  ctx[(t >> 6) * 68 + (t & 63)] = cval;
  __syncthreads();
  const float* wm = (j == 0) ? k_w : (j == 1) ? q_w : v_w;
  const float* bm = (j == 0) ? k_b : (j == 1) ? q_b : v_b;
  int d = t >> 3, s = t & 7;
  const float* wr = wm + d * CC + s * 64;
  const float* cl = ctx + s * 68;
  float a = 0.f;
#pragma unroll
  for (int c = 0; c < 64; c += 4) {
    float4 w4 = *reinterpret_cast<const float4*>(wr + c);
    a = fmaf(w4.x, cl[c + 0], a);
    a = fmaf(w4.y, cl[c + 1], a);
    a = fmaf(w4.z, cl[c + 2], a);
    a = fmaf(w4.w, cl[c + 3], a);
  }
  psum[d][s] = a;
  __syncthreads();
  if (t < 64) {
    float rsum = 0.f;
#pragma unroll
    for (int ss = 0; ss < 8; ss++) rsum += psum[t][ss];
    kqvbuf[((size_t)(b * 3 + j) * NH + h) * DK + t] = rsum + bm[t];
  }
}

// ---------------- K5: geometry + head softmax + out_ctx + MLP ----------------
// grid 16, block 512
__global__ __launch_bounds__(512) void k_attn_mlp(const float* __restrict__ kqvbuf,
    const float* __restrict__ meta,
    const float* __restrict__ g_w, const float* __restrict__ g_b,
    const float* __restrict__ aw1, const float* __restrict__ ab1,
    const float* __restrict__ lng, const float* __restrict__ lnb,
    const float* __restrict__ aw2, const float* __restrict__ ab2,
    float* __restrict__ add_term) {
  int b = blockIdx.x;
  int t = threadIdx.x;
  __shared__ float kq[3][NH * 68];
  __shared__ float smn[NH][NH];
  __shared__ float cxl[NH], cyl[NH];
  __shared__ float oc[CC];
  __shared__ float part[4][PL];
  __shared__ float yl[PL];
  __shared__ float sr[2][2];

  if (t < NH) { cxl[t] = meta[128 + b * NH + t]; cyl[t] = meta[256 + b * NH + t]; }
  {
    int h = t >> 6, d = t & 63;
#pragma unroll
    for (int j = 0; j < 3; j++)
      kq[j][h * 68 + d] = kqvbuf[(size_t)(b * 3 + j) * 512 + t];
  }
  __syncthreads();

  if (t < 64) {
    int m = t >> 3, n = t & 7;
    float dx = cxl[m] - cxl[n];
    float dy = cyl[m] - cyl[n];
    float pos[4] = { fmaxf(dx, 0.f), fmaxf(-dx, 0.f), fmaxf(dy, 0.f), fmaxf(-dy, 0.f) };
    float a = g_b[0];
#pragma unroll
    for (int p = 0; p < 4; p++) {
#pragma unroll
      for (int f = 0; f < 8; f++) {
        float dm = expf(-0.8634694098727671f * (float)f);  // 1000^(-f/8)
        float ang = 100.f * pos[p] * dm;
        a = fmaf(sinf(ang), g_w[p * 8 + f], a);
        a = fmaf(cosf(ang), g_w[32 + p * 8 + f], a);
      }
    }
    float wgl = logf(fmaxf(fmaxf(a, 0.f), 1e-6f));
    float dot = 0.f;
#pragma unroll
    for (int dd = 0; dd < DK; dd++)
      dot = fmaf(kq[0][m * 68 + dd], kq[1][n * 68 + dd], dot);
    smn[m][n] = dot * 0.125f + wgl;
  }
  __syncthreads();
  if (t < 8) {
    float mx = -1e30f;
#pragma unroll
    for (int m = 0; m < NH; m++) mx = fmaxf(mx, smn[m][t]);
    float ssum = 0.f; float ex[NH];
#pragma unroll
    for (int m = 0; m < NH; m++) { ex[m] = expf(smn[m][t] - mx); ssum += ex[m]; }
#pragma unroll
    for (int m = 0; m < NH; m++) smn[m][t] = ex[m] / ssum;
  }
  __syncthreads();
  {
    int n = t >> 6, d = t & 63;
    float a = 0.f;
#pragma unroll
    for (int m = 0; m < NH; m++) a = fmaf(smn[m][n], kq[2][m * 68 + d], a);
    oc[t] = a;
  }
  __syncthreads();
  {
    int d = t & 127, p = t >> 7;
    const float* wr = aw1 + d * CC + p * 128;
    const float* ol = oc + p * 128;
    float a = 0.f;
#pragma unroll 8
    for (int c = 0; c < 128; c += 4) {
      float4 w4 = *reinterpret_cast<const float4*>(wr + c);
      a = fmaf(w4.x, ol[c + 0], a);
      a = fmaf(w4.y, ol[c + 1], a);
      a = fmaf(w4.z, ol[c + 2], a);
      a = fmaf(w4.w, ol[c + 3], a);
    }
    part[p][d] = a;
  }
  __syncthreads();
  float y = 0.f;
  if (t < PL) y = part[0][t] + part[1][t] + part[2][t] + part[3][t] + ab1[t];
  {
    float s  = (t < PL) ? y : 0.f;
    float sq = s * y;
    s = wred_sum(s); sq = wred_sum(sq);
    if (t < PL && (t & 63) == 0) { sr[0][t >> 6] = s; sr[1][t >> 6] = sq; }
  }
  __syncthreads();
  {
    float mu = (sr[0][0] + sr[0][1]) * (1.f / 128.f);
    float var = (sr[1][0] + sr[1][1]) * (1.f / 128.f) - mu * mu;
    float rstd = rsqrtf(var + 1e-5f);
    if (t < PL) yl[t] = fmaxf((y - mu) * rstd * lng[t] + lnb[t], 0.f);
  }
  __syncthreads();
  {
    const float* wr = aw2 + t * PL;
    float a = ab2[t];
#pragma unroll 8
    for (int pp = 0; pp < PL; pp += 4) {
      float4 w4 = *reinterpret_cast<const float4*>(wr + pp);
      a = fmaf(w4.x, yl[pp + 0], a);
      a = fmaf(w4.y, yl[pp + 1], a);
      a = fmaf(w4.z, yl[pp + 2], a);
      a = fmaf(w4.w, yl[pp + 3], a);
    }
    add_term[b * CC + t] = a;
  }
}

// ---------------- K6: out = x + add_term[b][c] broadcast ----------------
__global__ __launch_bounds__(256) void k_add(const float* __restrict__ x,
                                             const float* __restrict__ add_term,
                                             float* __restrict__ out) {
  const float4* x4 = reinterpret_cast<const float4*>(x);
  float4* o4 = reinterpret_cast<float4*>(out);
  const size_t n4 = (size_t)BB * CC * HWH / 4;  // 8388608
  for (size_t i = (size_t)blockIdx.x * 256 + threadIdx.x; i < n4;
       i += (size_t)gridDim.x * 256) {
    float4 v = x4[i];
    float a = add_term[i >> 10];
    v.x += a; v.y += a; v.z += a; v.w += a;
    o4[i] = v;
  }
}

extern "C" void kernel_launch(void* const* d_in, const int* in_sizes, int n_in,
                              void* d_out, int out_size, void* d_ws, size_t ws_size,
                              hipStream_t stream) {
  const float* x   = (const float*)d_in[0];
  const float* cmw = (const float*)d_in[1];
  // d_in[2] conv_mask_b: per-head constant -> softmax-invariant, unused
  const float* g_w = (const float*)d_in[3];
  const float* g_b = (const float*)d_in[4];
  const float* k_w = (const float*)d_in[5];
  const float* k_b = (const float*)d_in[6];
  const float* q_w = (const float*)d_in[7];
  const float* q_b = (const float*)d_in[8];
  const float* v_w = (const float*)d_in[9];
  const float* v_b = (const float*)d_in[10];
  const float* aw1 = (const float*)d_in[11];
  const float* ab1 = (const float*)d_in[12];
  const float* lng = (const float*)d_in[13];
  const float* lnb = (const float*)d_in[14];
  const float* aw2 = (const float*)d_in[15];
  const float* ab2 = (const float*)d_in[16];
  float* out = (float*)d_out;
  float* ws = (float*)d_ws;

  // layout (floats). epart dead after k_softmax -> reused for pctx/kqvbuf/add_term.
  float* epart    = ws;                 // [8][16][8][4096] = 4,194,304 (16 MB)
  float* e        = ws + 4194304;       // [16][8][4096]    =   524,288
  float* meta     = ws + 4718592;       // 384 (pad 512)
  float* pctx     = ws;                 // [2][16][8][512]  =   131,072 (alias epart)
  float* kqvbuf   = ws + 131072;        // [16][3][8][64]   =    24,576 (alias epart)
  float* add_term = ws + 155648;        // [16][512]        =     8,192 (alias epart)

  hipLaunchKernelGGL(k_logits,   dim3(512),  dim3(256), 0, stream, x, cmw, epart);
  hipLaunchKernelGGL(k_softmax,  dim3(128),  dim3(256), 0, stream, epart, e, meta);
  hipLaunchKernelGGL(k_context,  dim3(512),  dim3(512), 0, stream, x, e, pctx);
  hipLaunchKernelGGL(k_kqv,      dim3(384),  dim3(512), 0, stream, pctx, meta,
                     k_w, q_w, v_w, k_b, q_b, v_b, kqvbuf);
  hipLaunchKernelGGL(k_attn_mlp, dim3(16),   dim3(512), 0, stream, kqvbuf, meta,
                     g_w, g_b, aw1, ab1, lng, lnb, aw2, ab2, add_term);
  hipLaunchKernelGGL(k_add,      dim3(2048), dim3(256), 0, stream, x, add_term, out);
}

// Round 7
// 149.908 us; speedup vs baseline: 1.0882x; 1.0099x over previous
//
#include <hip/hip_runtime.h>
#include <cmath>

#define BB 16
#define CC 512
#define HWH 4096
#define NH 8
#define DK 64
#define PL 128
#define CS 8   // c-split for logits

typedef float fx4 __attribute__((ext_vector_type(4)));

__device__ __forceinline__ float wred_sum(float v){
#pragma unroll
  for (int m = 32; m >= 1; m >>= 1) v += __shfl_xor(v, m, 64);
  return v;
}

// ---------------- K1: partial logits, c-split x8, float4 over p ----------------
// epart[cc][b][n][p] = sum_{c in chunk cc} x[b,c,p] * cmw[n,c]
// grid 512 = b(16) x ptile(4) x cc(8), block 256 (thread owns 4 positions)
__global__ __launch_bounds__(256) void k_logits(const float* __restrict__ x,
                                                const float* __restrict__ cmw,
                                                float* __restrict__ epart) {
  int bid = blockIdx.x;
  int cc = bid & 7;
  int tile = (bid >> 3) & 3;
  int b = bid >> 5;
  int p = tile * 1024 + threadIdx.x * 4;
  const float* xb = x + ((size_t)(b * CC + cc * 64)) * HWH + p;
  const float* wb = cmw + cc * 64;
  float acc[NH][4];
#pragma unroll
  for (int n = 0; n < NH; n++)
#pragma unroll
    for (int k = 0; k < 4; k++) acc[n][k] = 0.f;
#pragma unroll 8
  for (int c = 0; c < 64; c++) {
    float4 xv = *reinterpret_cast<const float4*>(xb + (size_t)c * HWH);
#pragma unroll
    for (int n = 0; n < NH; n++) {
      float w = wb[n * CC + c];
      acc[n][0] = fmaf(xv.x, w, acc[n][0]);
      acc[n][1] = fmaf(xv.y, w, acc[n][1]);
      acc[n][2] = fmaf(xv.z, w, acc[n][2]);
      acc[n][3] = fmaf(xv.w, w, acc[n][3]);
    }
  }
  float* ob = epart + (((size_t)(cc * BB + b)) * NH) * HWH + p;
#pragma unroll
  for (int n = 0; n < NH; n++) {
    float4 o = make_float4(acc[n][0], acc[n][1], acc[n][2], acc[n][3]);
    *reinterpret_cast<float4*>(ob + (size_t)n * HWH) = o;
  }
}

// ---------------- K2: sum 8 partials + per-(b,n) softmax over 4096 ----------------
// stores UNNORMALIZED exp into e; meta[0..127]=inv_sum,[128..255]=cx,[256..383]=cy
// grid 128, block 256 (thread owns 4 chunks of float4)
__global__ __launch_bounds__(256) void k_softmax(const float* __restrict__ epart,
                                                 float* __restrict__ e,
                                                 float* __restrict__ meta) {
  __shared__ float sr[4][4];
  int bn = blockIdx.x;
  int t = threadIdx.x;
  float* row = e + (size_t)bn * HWH;
  float4 v[4];
  float lmax = -1e30f;
#pragma unroll
  for (int i = 0; i < 4; i++) {
    int idx = t * 4 + i * 1024;
    const float* r = epart + (size_t)bn * HWH + idx;
    float4 a = *reinterpret_cast<const float4*>(r);
#pragma unroll
    for (int cc = 1; cc < CS; cc++) {
      float4 pth = *reinterpret_cast<const float4*>(r + (size_t)cc * BB * NH * HWH);
      a.x += pth.x; a.y += pth.y; a.z += pth.z; a.w += pth.w;
    }
    v[i] = a;
    lmax = fmaxf(lmax, fmaxf(fmaxf(a.x, a.y), fmaxf(a.z, a.w)));
  }
#pragma unroll
  for (int m = 32; m >= 1; m >>= 1) lmax = fmaxf(lmax, __shfl_xor(lmax, m, 64));
  if ((t & 63) == 0) sr[0][t >> 6] = lmax;
  __syncthreads();
  lmax = fmaxf(fmaxf(sr[0][0], sr[0][1]), fmaxf(sr[0][2], sr[0][3]));
  float s = 0.f, sc = 0.f, sy = 0.f;
#pragma unroll
  for (int i = 0; i < 4; i++) {
    int idx = t * 4 + i * 1024;
    float4 ev;
    ev.x = expf(v[i].x - lmax);
    ev.y = expf(v[i].y - lmax);
    ev.z = expf(v[i].z - lmax);
    ev.w = expf(v[i].w - lmax);
    *reinterpret_cast<float4*>(row + idx) = ev;
    float col = (float)(idx & 63);
    float rw  = (float)(idx >> 6);
    s += ev.x + ev.y + ev.z + ev.w;
    sc += ev.x * col + ev.y * (col + 1.f) + ev.z * (col + 2.f) + ev.w * (col + 3.f);
    sy += (ev.x + ev.y + ev.z + ev.w) * rw;
  }
  s = wred_sum(s); sc = wred_sum(sc); sy = wred_sum(sy);
  if ((t & 63) == 0) { sr[1][t >> 6] = s; sr[2][t >> 6] = sc; sr[3][t >> 6] = sy; }
  __syncthreads();
  if (t == 0) {
    s  = sr[1][0] + sr[1][1] + sr[1][2] + sr[1][3];
    sc = sr[2][0] + sr[2][1] + sr[2][2] + sr[2][3];
    sy = sr[3][0] + sr[3][1] + sr[3][2] + sr[3][3];
    meta[bn]       = 1.f / s;
    meta[128 + bn] = sc / (s * 64.f);   // cx
    meta[256 + bn] = sy / (s * 64.f);   // cy
  }
}

// ---------------- K3: context, register-only ----------------
// pctx[ng][b][h][c] = sum_{n in half ng} x[b,c,n] * e[b,h,n]
// grid 512 = b(16) x cg(16) x ng(2), block 512 = 8 waves.
__global__ __launch_bounds__(512) void k_context(const float* __restrict__ x,
                                                 const float* __restrict__ e,
                                                 float* __restrict__ pctx) {
  int bid = blockIdx.x;
  int ng = bid & 1;
  int cg = (bid >> 1) & 15;
  int b = bid >> 5;
  int w = threadIdx.x >> 6;
  int l = threadIdx.x & 63;
  int cbase = cg * 32 + w * 4;
  const float* xb = x + ((size_t)(b * CC + cbase)) * HWH + ng * 2048 + l * 4;
  const float* eb = e + (size_t)b * NH * HWH + ng * 2048 + l * 4;
  float acc[4][NH];
#pragma unroll
  for (int ci = 0; ci < 4; ci++)
#pragma unroll
    for (int h = 0; h < NH; h++) acc[ci][h] = 0.f;

#pragma unroll 2
  for (int ch = 0; ch < 8; ch++) {   // 8 chunks of 256 n
    int off = ch * 256;
    float4 ev[NH];
#pragma unroll
    for (int h = 0; h < NH; h++)
      ev[h] = *reinterpret_cast<const float4*>(eb + (size_t)h * HWH + off);
#pragma unroll
    for (int ci = 0; ci < 4; ci++) {
      float4 xv = *reinterpret_cast<const float4*>(xb + (size_t)ci * HWH + off);
#pragma unroll
      for (int h = 0; h < NH; h++) {
        float a = acc[ci][h];
        a = fmaf(xv.x, ev[h].x, a);
        a = fmaf(xv.y, ev[h].y, a);
        a = fmaf(xv.z, ev[h].z, a);
        a = fmaf(xv.w, ev[h].w, a);
        acc[ci][h] = a;
      }
    }
  }
#pragma unroll
  for (int ci = 0; ci < 4; ci++)
#pragma unroll
    for (int h = 0; h < NH; h++) acc[ci][h] = wred_sum(acc[ci][h]);
  if (l == 0) {
    float* op = pctx + (((size_t)(ng * BB + b)) * NH) * CC + cbase;
#pragma unroll
    for (int h = 0; h < NH; h++)
#pragma unroll
      for (int ci = 0; ci < 4; ci++) op[h * CC + ci] = acc[ci][h];
  }
}

// ---------------- K4: kqv projections, 8-way split dots ----------------
// grid 384 = b(16) x j(3) x h(8), block 512
__global__ __launch_bounds__(512) void k_kqv(const float* __restrict__ pctx,
    const float* __restrict__ meta,
    const float* __restrict__ k_w, const float* __restrict__ q_w,
    const float* __restrict__ v_w,
    const float* __restrict__ k_b, const float* __restrict__ q_b,
    const float* __restrict__ v_b,
    float* __restrict__ kqvbuf) {
  int bid = blockIdx.x;
  int b = bid / 24;
  int r = bid - b * 24;
  int j = r >> 3;
  int h = r & 7;
  int t = threadIdx.x;
  __shared__ float ctx[8 * 68];
  __shared__ float psum[64][9];
  float inv = meta[b * NH + h];
  size_t base = ((size_t)b * NH + h) * CC + t;
  float cval = (pctx[base] + pctx[(size_t)BB * NH * CC + base]) * inv;
  ctx[(t >> 6) * 68 + (t & 63)] = cval;
  __syncthreads();
  const float* wm = (j == 0) ? k_w : (j == 1) ? q_w : v_w;
  const float* bm = (j == 0) ? k_b : (j == 1) ? q_b : v_b;
  int d = t >> 3, s = t & 7;
  const float* wr = wm + d * CC + s * 64;
  const float* cl = ctx + s * 68;
  float a = 0.f;
#pragma unroll
  for (int c = 0; c < 64; c += 4) {
    float4 w4 = *reinterpret_cast<const float4*>(wr + c);
    a = fmaf(w4.x, cl[c + 0], a);
    a = fmaf(w4.y, cl[c + 1], a);
    a = fmaf(w4.z, cl[c + 2], a);
    a = fmaf(w4.w, cl[c + 3], a);
  }
  psum[d][s] = a;
  __syncthreads();
  if (t < 64) {
    float rsum = 0.f;
#pragma unroll
    for (int ss = 0; ss < 8; ss++) rsum += psum[t][ss];
    kqvbuf[((size_t)(b * 3 + j) * NH + h) * DK + t] = rsum + bm[t];
  }
}

// ---------------- K5: geometry + head softmax + out_ctx + MLP ----------------
// grid 16, block 512
__global__ __launch_bounds__(512) void k_attn_mlp(const float* __restrict__ kqvbuf,
    const float* __restrict__ meta,
    const float* __restrict__ g_w, const float* __restrict__ g_b,
    const float* __restrict__ aw1, const float* __restrict__ ab1,
    const float* __restrict__ lng, const float* __restrict__ lnb,
    const float* __restrict__ aw2, const float* __restrict__ ab2,
    float* __restrict__ add_term) {
  int b = blockIdx.x;
  int t = threadIdx.x;
  __shared__ float kq[3][NH * 68];
  __shared__ float smn[NH][NH];
  __shared__ float cxl[NH], cyl[NH];
  __shared__ float oc[CC];
  __shared__ float part[4][PL];
  __shared__ float yl[PL];
  __shared__ float sr[2][2];

  if (t < NH) { cxl[t] = meta[128 + b * NH + t]; cyl[t] = meta[256 + b * NH + t]; }
  {
    int h = t >> 6, d = t & 63;
#pragma unroll
    for (int j = 0; j < 3; j++)
      kq[j][h * 68 + d] = kqvbuf[(size_t)(b * 3 + j) * 512 + t];
  }
  __syncthreads();

  if (t < 64) {
    int m = t >> 3, n = t & 7;
    float dx = cxl[m] - cxl[n];
    float dy = cyl[m] - cyl[n];
    float pos[4] = { fmaxf(dx, 0.f), fmaxf(-dx, 0.f), fmaxf(dy, 0.f), fmaxf(-dy, 0.f) };
    float a = g_b[0];
#pragma unroll
    for (int p = 0; p < 4; p++) {
#pragma unroll
      for (int f = 0; f < 8; f++) {
        float dm = expf(-0.8634694098727671f * (float)f);  // 1000^(-f/8)
        float ang = 100.f * pos[p] * dm;
        a = fmaf(sinf(ang), g_w[p * 8 + f], a);
        a = fmaf(cosf(ang), g_w[32 + p * 8 + f], a);
      }
    }
    float wgl = logf(fmaxf(fmaxf(a, 0.f), 1e-6f));
    float dot = 0.f;
#pragma unroll
    for (int dd = 0; dd < DK; dd++)
      dot = fmaf(kq[0][m * 68 + dd], kq[1][n * 68 + dd], dot);
    smn[m][n] = dot * 0.125f + wgl;
  }
  __syncthreads();
  if (t < 8) {
    float mx = -1e30f;
#pragma unroll
    for (int m = 0; m < NH; m++) mx = fmaxf(mx, smn[m][t]);
    float ssum = 0.f; float ex[NH];
#pragma unroll
    for (int m = 0; m < NH; m++) { ex[m] = expf(smn[m][t] - mx); ssum += ex[m]; }
#pragma unroll
    for (int m = 0; m < NH; m++) smn[m][t] = ex[m] / ssum;
  }
  __syncthreads();
  {
    int n = t >> 6, d = t & 63;
    float a = 0.f;
#pragma unroll
    for (int m = 0; m < NH; m++) a = fmaf(smn[m][n], kq[2][m * 68 + d], a);
    oc[t] = a;
  }
  __syncthreads();
  {
    int d = t & 127, p = t >> 7;
    const float* wr = aw1 + d * CC + p * 128;
    const float* ol = oc + p * 128;
    float a = 0.f;
#pragma unroll 8
    for (int c = 0; c < 128; c += 4) {
      float4 w4 = *reinterpret_cast<const float4*>(wr + c);
      a = fmaf(w4.x, ol[c + 0], a);
      a = fmaf(w4.y, ol[c + 1], a);
      a = fmaf(w4.z, ol[c + 2], a);
      a = fmaf(w4.w, ol[c + 3], a);
    }
    part[p][d] = a;
  }
  __syncthreads();
  float y = 0.f;
  if (t < PL) y = part[0][t] + part[1][t] + part[2][t] + part[3][t] + ab1[t];
  {
    float s  = (t < PL) ? y : 0.f;
    float sq = s * y;
    s = wred_sum(s); sq = wred_sum(sq);
    if (t < PL && (t & 63) == 0) { sr[0][t >> 6] = s; sr[1][t >> 6] = sq; }
  }
  __syncthreads();
  {
    float mu = (sr[0][0] + sr[0][1]) * (1.f / 128.f);
    float var = (sr[1][0] + sr[1][1]) * (1.f / 128.f) - mu * mu;
    float rstd = rsqrtf(var + 1e-5f);
    if (t < PL) yl[t] = fmaxf((y - mu) * rstd * lng[t] + lnb[t], 0.f);
  }
  __syncthreads();
  {
    const float* wr = aw2 + t * PL;
    float a = ab2[t];
#pragma unroll 8
    for (int pp = 0; pp < PL; pp += 4) {
      float4 w4 = *reinterpret_cast<const float4*>(wr + pp);
      a = fmaf(w4.x, yl[pp + 0], a);
      a = fmaf(w4.y, yl[pp + 1], a);
      a = fmaf(w4.z, yl[pp + 2], a);
      a = fmaf(w4.w, yl[pp + 3], a);
    }
    add_term[b * CC + t] = a;
  }
}

// ---------------- K6: out = x + add_term[b][c], nontemporal out stores ----------------
// out is never re-read on device -> nt store keeps x/epart/e L3-resident (152 MB < 256 MB)
__global__ __launch_bounds__(256) void k_add(const float* __restrict__ x,
                                             const float* __restrict__ add_term,
                                             float* __restrict__ out) {
  const fx4* x4 = reinterpret_cast<const fx4*>(x);
  fx4* o4 = reinterpret_cast<fx4*>(out);
  const size_t n4 = (size_t)BB * CC * HWH / 4;  // 8388608
  for (size_t i = (size_t)blockIdx.x * 256 + threadIdx.x; i < n4;
       i += (size_t)gridDim.x * 256) {
    fx4 v = x4[i];
    float a = add_term[i >> 10];
    v += a;
    __builtin_nontemporal_store(v, &o4[i]);
  }
}

extern "C" void kernel_launch(void* const* d_in, const int* in_sizes, int n_in,
                              void* d_out, int out_size, void* d_ws, size_t ws_size,
                              hipStream_t stream) {
  const float* x   = (const float*)d_in[0];
  const float* cmw = (const float*)d_in[1];
  // d_in[2] conv_mask_b: per-head constant -> softmax-invariant, unused
  const float* g_w = (const float*)d_in[3];
  const float* g_b = (const float*)d_in[4];
  const float* k_w = (const float*)d_in[5];
  const float* k_b = (const float*)d_in[6];
  const float* q_w = (const float*)d_in[7];
  const float* q_b = (const float*)d_in[8];
  const float* v_w = (const float*)d_in[9];
  const float* v_b = (const float*)d_in[10];
  const float* aw1 = (const float*)d_in[11];
  const float* ab1 = (const float*)d_in[12];
  const float* lng = (const float*)d_in[13];
  const float* lnb = (const float*)d_in[14];
  const float* aw2 = (const float*)d_in[15];
  const float* ab2 = (const float*)d_in[16];
  float* out = (float*)d_out;
  float* ws = (float*)d_ws;

  // layout (floats). epart dead after k_softmax -> reused for pctx/kqvbuf/add_term.
  float* epart    = ws;                 // [8][16][8][4096] = 4,194,304 (16 MB)
  float* e        = ws + 4194304;       // [16][8][4096]    =   524,288
  float* meta     = ws + 4718592;       // 384 (pad 512)
  float* pctx     = ws;                 // [2][16][8][512]  =   131,072 (alias epart)
  float* kqvbuf   = ws + 131072;        // [16][3][8][64]   =    24,576 (alias epart)
  float* add_term = ws + 155648;        // [16][512]        =     8,192 (alias epart)

  hipLaunchKernelGGL(k_logits,   dim3(512),  dim3(256), 0, stream, x, cmw, epart);
  hipLaunchKernelGGL(k_softmax,  dim3(128),  dim3(256), 0, stream, epart, e, meta);
  hipLaunchKernelGGL(k_context,  dim3(512),  dim3(512), 0, stream, x, e, pctx);
  hipLaunchKernelGGL(k_kqv,      dim3(384),  dim3(512), 0, stream, pctx, meta,
                     k_w, q_w, v_w, k_b, q_b, v_b, kqvbuf);
  hipLaunchKernelGGL(k_attn_mlp, dim3(16),   dim3(512), 0, stream, kqvbuf, meta,
                     g_w, g_b, aw1, ab1, lng, lnb, aw2, ab2, add_term);
  hipLaunchKernelGGL(k_add,      dim3(2048), dim3(256), 0, stream, x, add_term, out);
}